// Round 17
// baseline (93.514 us; speedup 1.0000x reference)
//
#include <hip/hip_runtime.h>

#define KS 21
#define CC 10
#define H 128
#define W 128
#define HW (H*W)
#define NCH 3
#define B 4
#define NSPLIT 2               // x-splits per row
#define HWX 64                 // px per block
#define PWX (HWX + 2*CC)       // 84 data slots per staged row

typedef _Float16 half4v __attribute__((ext_vector_type(4)));
struct __attribute__((packed)) f4u { float v[4]; };   // 4B-aligned 16B load

// LDS: dt[21][PWX] packed half4 {d0,d1,d2,0} = 14112 B; sacc [16][65] float4
// = 16640 B aliases it after a barrier. Size = max of the two.
#define SMEM_BYTES (16*65*16)

// grid (H, 2, B), block 256 = 16 workers x 16 px-quads, 4 blocks/CU.
// Worker w takes taps T = w, w+16, ... — padded to a UNIFORM 28 iterations
// (taps T>440 are masked to exact +0.0 through clamped-safe addresses) so the
// tap loop FULLY UNROLLS and the compiler can keep many independent kern
// dwordx4 loads in flight (the H2 = MLP-depth experiment; 128-VGPR budget).
// Tap T: plane Q=440-T, row py=y+T/21-10, cols c0..c0+3 (c0=x0+4t+T%21-10).
// (i,j,Q) incremental. Epilogue: fixed-order 16-worker in-LDS reduce +
// closed-form OOB denom + divide. No atomics, no fences, deterministic.
__global__ __launch_bounds__(256, 4)
void kaw_gather(const float* __restrict__ data,
                const float* __restrict__ kern,
                float* __restrict__ out,
                float* __restrict__ sumw)
{
    __shared__ __align__(16) unsigned char smem[SMEM_BYTES];
    unsigned char* dtB = smem;

    const int tid = threadIdx.x;
    const int w  = tid >> 4;        // tap worker 0..15
    const int t  = tid & 15;        // px quad within the half-row
    const int y  = blockIdx.x;
    const int x0 = blockIdx.y * HWX;
    const int b  = blockIdx.z;

    const float* __restrict__ kbase = kern + (size_t)b * (KS * KS) * HW;
    const float* __restrict__ dbase = data + (size_t)b * NCH * HW;

    // ---- stage data rows y-10..y+10, cols x0-10..x0+73, f16 {d0,d1,d2,0} ----
    for (int e = tid; e < 21 * PWX; e += 256) {
        int r  = e / PWX;                    // compiler magic-div (exact)
        int c  = e - r * PWX;
        int gy = y + r - CC;
        int gx = x0 + c - CC;
        half4v v = (half4v){(_Float16)0, (_Float16)0, (_Float16)0, (_Float16)0};
        if ((unsigned)gy < (unsigned)H && (unsigned)gx < (unsigned)W) {
            v.x = (_Float16)dbase[(0 * H + gy) * W + gx];
            v.y = (_Float16)dbase[(1 * H + gy) * W + gx];
            v.z = (_Float16)dbase[(2 * H + gy) * W + gx];
        }
        *reinterpret_cast<half4v*>(dtB + e * 8) = v;
    }
    __syncthreads();

    // ---- 16 accumulators: 4 px x {ch0, ch1, ch2, w} ----
    float a00 = 0.f, a01 = 0.f, a02 = 0.f, aw0 = 0.f;
    float a10 = 0.f, a11 = 0.f, a12 = 0.f, aw1 = 0.f;
    float a20 = 0.f, a21 = 0.f, a22 = 0.f, aw2 = 0.f;
    float a30 = 0.f, a31 = 0.f, a32 = 0.f, aw3 = 0.f;

    // Uniform 28 taps/worker: T = w + 16k, k = 0..27 (T<=447; T>440 masked).
    int i = 0, j = w, Q = 440 - w;          // w < 16 < 21
    #pragma unroll
    for (int k = 0; k < 28; ++k) {
        bool tv = (Q >= 0);                  // T <= 440 (real tap)
        int Qc = tv ? Q : 0;                 // safe plane
        int ic = (i < KS) ? i : (KS - 1);    // safe data row (i<=21)
        int py = y + i - CC;
        bool rv = tv && ((unsigned)py < (unsigned)H);
        int pyc = py < 0 ? 0 : (py > H - 1 ? H - 1 : py);
        int c0 = x0 + 4 * t + j - CC;        // global kern/data col of elem 0
        // c0 < 0 only when x0==0, where Q>=1 for real taps -> in-bounds addr.
        f4u g = *reinterpret_cast<const f4u*>(
            kbase + ((Qc << 14) + (pyc << 7) + c0));
        float e0 = (rv && (unsigned)(c0 + 0) < (unsigned)W) ? __expf(g.v[0]) : 0.f;
        float e1 = (rv && (unsigned)(c0 + 1) < (unsigned)W) ? __expf(g.v[1]) : 0.f;
        float e2 = (rv && (unsigned)(c0 + 2) < (unsigned)W) ? __expf(g.v[2]) : 0.f;
        float e3 = (rv && (unsigned)(c0 + 3) < (unsigned)W) ? __expf(g.v[3]) : 0.f;
        const unsigned char* dp = dtB + (unsigned)(ic * PWX + 4 * t + j) * 8;
        half4v d0 = *reinterpret_cast<const half4v*>(dp +  0);
        half4v d1 = *reinterpret_cast<const half4v*>(dp +  8);
        half4v d2 = *reinterpret_cast<const half4v*>(dp + 16);
        half4v d3 = *reinterpret_cast<const half4v*>(dp + 24);
        a00 += e0 * (float)d0.x; a01 += e0 * (float)d0.y; a02 += e0 * (float)d0.z; aw0 += e0;
        a10 += e1 * (float)d1.x; a11 += e1 * (float)d1.y; a12 += e1 * (float)d1.z; aw1 += e1;
        a20 += e2 * (float)d2.x; a21 += e2 * (float)d2.y; a22 += e2 * (float)d2.z; aw2 += e2;
        a30 += e3 * (float)d3.x; a31 += e3 * (float)d3.y; a32 += e3 * (float)d3.z; aw3 += e3;
        // advance T += 16: j += 16 (mod 21, wraps at most once), Q -= 16
        j += 16; Q -= 16;
        if (j >= KS) { j -= KS; ++i; }
    }

    // ---- fixed-order cross-worker reduce (sacc aliases the data tile) ----
    __syncthreads();                          // all dt reads done
    float4* sacc = (float4*)smem;             // [16][65] float4, padded stride
    sacc[w * 65 + 4 * t + 0] = make_float4(a00, a01, a02, aw0);
    sacc[w * 65 + 4 * t + 1] = make_float4(a10, a11, a12, aw1);
    sacc[w * 65 + 4 * t + 2] = make_float4(a20, a21, a22, aw2);
    sacc[w * 65 + 4 * t + 3] = make_float4(a30, a31, a32, aw3);
    __syncthreads();
    if (tid < HWX) {
        const int lp = tid;
        const int px = x0 + lp;
        float r0 = 0.f, r1 = 0.f, r2 = 0.f, rw = 0.f;
        #pragma unroll
        for (int s = 0; s < 16; ++s) {        // fixed order -> deterministic
            float4 p = sacc[s * 65 + lp];
            r0 += p.x; r1 += p.y; r2 += p.z; rw += p.w;
        }
        // OOB taps contribute exp(0)=1 each to the softmax denominator
        int nry = max(0, CC - y)  + max(0, y  - (H - 1 - CC));
        int nrx = max(0, CC - px) + max(0, px - (W - 1 - CC));
        float co = 21.f * nry + (float)((21 - nry) * nrx);
        float inv = 1.0f / (rw + co);
        const size_t o = (size_t)b * NCH * HW + (size_t)y * W + px;
        out[o]          = r0 * inv;
        out[o + HW]     = r1 * inv;
        out[o + 2 * HW] = r2 * inv;
        sumw[(size_t)b * HW + (size_t)y * W + px] = rw * inv;
    }
}

extern "C" void kernel_launch(void* const* d_in, const int* in_sizes, int n_in,
                              void* d_out, int out_size, void* d_ws, size_t ws_size,
                              hipStream_t stream)
{
    const float* data = (const float*)d_in[0];   // (4,3,128,128) f32
    const float* kern = (const float*)d_in[1];   // (4,441,128,128) f32
    float* out  = (float*)d_out;                 // (4,3,128,128)
    float* sumw = out + (size_t)B * NCH * HW;    // (4,1,128,128)

    dim3 g(H, NSPLIT, B);
    kaw_gather<<<g, 256, 0, stream>>>(data, kern, out, sumw);
}

// Round 18
// 30.014 us; speedup vs baseline: 3.1157x; 3.1157x over previous
//
#include <hip/hip_runtime.h>

#define KS 21
#define CC 10
#define H 128
#define W 128
#define HW (H*W)
#define NCH 3
#define B 4
#define NSPLIT 4               // x-splits per row
#define HWX 32                 // px per block
#define PWX (HWX + 2*CC)       // 52 data slots per staged row

typedef _Float16 half4v __attribute__((ext_vector_type(4)));
struct __attribute__((packed)) f4u { float v[4]; };   // 4B-aligned 16B load

// LDS: dt[21][PWX] packed half4 {d0,d1,d2,valid} = 8736 B; sacc [32][33]
// float4 = 16896 B aliases it after a barrier. Size = max of the two.
#define SMEM_BYTES (32*33*16)

// grid (H, 4, B), block 256 = 32 workers x 8 px-quads (round-16 structure,
// 30.5 us). This round's single change: validity-fold — the data tile's 4th
// f16 channel holds 1.0 iff (row,col) is in-bounds, so the tap loop has NO
// compares/cndmasks: a0..a2 += e*d (d=0 when OOB), aw += e*d.w (w=0 when
// OOB). Clamped kern addresses always read real bounded kern values, and
// exp(bounded)*0 = +0 exactly -> bit-identical to the masked version.
// Epilogue: fixed-order 32-worker in-LDS reduce + closed-form OOB denom +
// divide. No atomics, no fences, fully deterministic.
__global__ __launch_bounds__(256, 8)
void kaw_gather(const float* __restrict__ data,
                const float* __restrict__ kern,
                float* __restrict__ out,
                float* __restrict__ sumw)
{
    __shared__ __align__(16) unsigned char smem[SMEM_BYTES];
    unsigned char* dtB = smem;

    const int tid = threadIdx.x;
    const int w  = tid >> 3;        // tap worker 0..31
    const int t  = tid & 7;         // px quad within the quarter-row
    const int y  = blockIdx.x;
    const int x0 = blockIdx.y * HWX;
    const int b  = blockIdx.z;

    const float* __restrict__ kbase = kern + (size_t)b * (KS * KS) * HW;
    const float* __restrict__ dbase = data + (size_t)b * NCH * HW;

    // ---- stage data rows y-10..y+10, cols x0-10..x0+41 ----
    // {d0,d1,d2,valid}: valid=1.0 iff the (row,col) is inside the image.
    for (int e = tid; e < 21 * PWX; e += 256) {
        int r  = e / PWX;                    // compiler magic-div (exact)
        int c  = e - r * PWX;
        int gy = y + r - CC;
        int gx = x0 + c - CC;
        half4v v = (half4v){(_Float16)0, (_Float16)0, (_Float16)0, (_Float16)0};
        if ((unsigned)gy < (unsigned)H && (unsigned)gx < (unsigned)W) {
            v.x = (_Float16)dbase[(0 * H + gy) * W + gx];
            v.y = (_Float16)dbase[(1 * H + gy) * W + gx];
            v.z = (_Float16)dbase[(2 * H + gy) * W + gx];
            v.w = (_Float16)1.0f;
        }
        *reinterpret_cast<half4v*>(dtB + e * 8) = v;
    }
    __syncthreads();

    // ---- 16 accumulators: 4 px x {ch0, ch1, ch2, w} ----
    float a00 = 0.f, a01 = 0.f, a02 = 0.f, aw0 = 0.f;
    float a10 = 0.f, a11 = 0.f, a12 = 0.f, aw1 = 0.f;
    float a20 = 0.f, a21 = 0.f, a22 = 0.f, aw2 = 0.f;
    float a30 = 0.f, a31 = 0.f, a32 = 0.f, aw3 = 0.f;

    // 441 = 32*13 + 25: workers 0..24 take 14 taps, 25..31 take 13.
    const int ntap = (w < 25) ? 14 : 13;
    int i = (w >= KS) ? 1 : 0;
    int j = (w >= KS) ? w - KS : w;
    int Q = 440 - w;
    #pragma unroll 4
    for (int k = 0; k < ntap; ++k) {
        int py  = y + i - CC;
        int pyc = py < 0 ? 0 : (py > H - 1 ? H - 1 : py);   // addr-safe row
        int c0  = x0 + 4 * t + j - CC;       // global kern/data col of elem 0
        // c0 < 0 only when x0==0, where Q >= 1 -> address stays in-bounds.
        f4u g = *reinterpret_cast<const f4u*>(
            kbase + ((Q << 14) + (pyc << 7) + c0));
        float e0 = __expf(g.v[0]);
        float e1 = __expf(g.v[1]);
        float e2 = __expf(g.v[2]);
        float e3 = __expf(g.v[3]);
        const unsigned char* dp = dtB + (unsigned)(i * PWX + 4 * t + j) * 8;
        half4v d0 = *reinterpret_cast<const half4v*>(dp +  0);
        half4v d1 = *reinterpret_cast<const half4v*>(dp +  8);
        half4v d2 = *reinterpret_cast<const half4v*>(dp + 16);
        half4v d3 = *reinterpret_cast<const half4v*>(dp + 24);
        a00 += e0 * (float)d0.x; a01 += e0 * (float)d0.y; a02 += e0 * (float)d0.z; aw0 += e0 * (float)d0.w;
        a10 += e1 * (float)d1.x; a11 += e1 * (float)d1.y; a12 += e1 * (float)d1.z; aw1 += e1 * (float)d1.w;
        a20 += e2 * (float)d2.x; a21 += e2 * (float)d2.y; a22 += e2 * (float)d2.z; aw2 += e2 * (float)d2.w;
        a30 += e3 * (float)d3.x; a31 += e3 * (float)d3.y; a32 += e3 * (float)d3.z; aw3 += e3 * (float)d3.w;
        // advance T += 32: j += 32 (mod 21, wraps at most twice), Q -= 32
        j += 32; Q -= 32;
        if (j >= KS) { j -= KS; ++i; }
        if (j >= KS) { j -= KS; ++i; }
    }

    // ---- fixed-order cross-worker reduce (sacc aliases the data tile) ----
    __syncthreads();                          // all dt reads done
    float4* sacc = (float4*)smem;             // [32][33] float4, padded stride
    sacc[w * 33 + 4 * t + 0] = make_float4(a00, a01, a02, aw0);
    sacc[w * 33 + 4 * t + 1] = make_float4(a10, a11, a12, aw1);
    sacc[w * 33 + 4 * t + 2] = make_float4(a20, a21, a22, aw2);
    sacc[w * 33 + 4 * t + 3] = make_float4(a30, a31, a32, aw3);
    __syncthreads();
    if (tid < HWX) {
        const int lp = tid;
        const int px = x0 + lp;
        float r0 = 0.f, r1 = 0.f, r2 = 0.f, rw = 0.f;
        #pragma unroll
        for (int s = 0; s < 32; ++s) {        // fixed order -> deterministic
            float4 p = sacc[s * 33 + lp];
            r0 += p.x; r1 += p.y; r2 += p.z; rw += p.w;
        }
        // OOB taps contribute exp(0)=1 each to the softmax denominator
        int nry = max(0, CC - y)  + max(0, y  - (H - 1 - CC));
        int nrx = max(0, CC - px) + max(0, px - (W - 1 - CC));
        float co = 21.f * nry + (float)((21 - nry) * nrx);
        float inv = 1.0f / (rw + co);
        const size_t o = (size_t)b * NCH * HW + (size_t)y * W + px;
        out[o]          = r0 * inv;
        out[o + HW]     = r1 * inv;
        out[o + 2 * HW] = r2 * inv;
        sumw[(size_t)b * HW + (size_t)y * W + px] = rw * inv;
    }
}

extern "C" void kernel_launch(void* const* d_in, const int* in_sizes, int n_in,
                              void* d_out, int out_size, void* d_ws, size_t ws_size,
                              hipStream_t stream)
{
    const float* data = (const float*)d_in[0];   // (4,3,128,128) f32
    const float* kern = (const float*)d_in[1];   // (4,441,128,128) f32
    float* out  = (float*)d_out;                 // (4,3,128,128)
    float* sumw = out + (size_t)B * NCH * HW;    // (4,1,128,128)

    dim3 g(H, NSPLIT, B);
    kaw_gather<<<g, 256, 0, stream>>>(data, kern, out, sumw);
}

// Round 19
// 29.655 us; speedup vs baseline: 3.1534x; 1.0121x over previous
//
#include <hip/hip_runtime.h>

#define KS 21
#define CC 10
#define H 128
#define W 128
#define HW (H*W)
#define NCH 3
#define B 4
#define PW (W + 2*CC)          // 148 data slots per staged row

typedef _Float16 half4v __attribute__((ext_vector_type(4)));
struct __attribute__((packed)) f4u { float v[4]; };   // 4B-aligned 16B load

// LDS: dt[21][PW] packed half4 {d0,d1,d2,valid} = 24864 B; sacc [16][129]
// float4 = 33024 B aliases it after a barrier. Size = max of the two.
#define SMEM_BYTES (16*129*16)

// grid (H, B), block 512 = 16 workers x 32 px-quads. Block = one FULL row
// (b,y); quad t owns px 4t..4t+3, worker w = tid>>5 takes taps T = w+16k.
// KEY CHANGE vs r18: lane map t = tid&31 makes each half-wave (one worker)
// read one kern plane's full row = 512 B CONTIGUOUS per plane per wave-load
// (vs 128 B granules in all prior rounds) — the DRAM-burst-granule test.
// Validity-fold: data tile 4th f16 channel = 1.0 iff in-bounds; tap loop has
// no compares (OOB -> exact +0; clamped addrs read real bounded kern floats,
// max overhang 536 B stays inside batch b's 441 planes).
// Epilogue: fixed-order 16-worker in-LDS reduce + closed-form OOB denom +
// divide. No atomics, no fences, fully deterministic.
__global__ __launch_bounds__(512, 2)
void kaw_gather(const float* __restrict__ data,
                const float* __restrict__ kern,
                float* __restrict__ out,
                float* __restrict__ sumw)
{
    __shared__ __align__(16) unsigned char smem[SMEM_BYTES];
    unsigned char* dtB = smem;

    const int tid = threadIdx.x;
    const int t = tid & 31;         // px quad: px 4t..4t+3 (full row)
    const int w = tid >> 5;         // tap worker 0..15
    const int y = blockIdx.x;
    const int b = blockIdx.y;

    const float* __restrict__ kbase = kern + (size_t)b * (KS * KS) * HW;
    const float* __restrict__ dbase = data + (size_t)b * NCH * HW;

    // ---- stage data rows y-10..y+10, cols -10..137, f16 {d0,d1,d2,valid} ----
    for (int e = tid; e < 21 * PW; e += 512) {
        int r  = e / PW;                     // compiler magic-div (exact)
        int c  = e - r * PW;
        int gy = y + r - CC;
        int gx = c - CC;
        half4v v = (half4v){(_Float16)0, (_Float16)0, (_Float16)0, (_Float16)0};
        if ((unsigned)gy < (unsigned)H && (unsigned)gx < (unsigned)W) {
            v.x = (_Float16)dbase[(0 * H + gy) * W + gx];
            v.y = (_Float16)dbase[(1 * H + gy) * W + gx];
            v.z = (_Float16)dbase[(2 * H + gy) * W + gx];
            v.w = (_Float16)1.0f;
        }
        *reinterpret_cast<half4v*>(dtB + e * 8) = v;
    }
    __syncthreads();

    // ---- 16 accumulators: 4 px x {ch0, ch1, ch2, w} ----
    float a00 = 0.f, a01 = 0.f, a02 = 0.f, aw0 = 0.f;
    float a10 = 0.f, a11 = 0.f, a12 = 0.f, aw1 = 0.f;
    float a20 = 0.f, a21 = 0.f, a22 = 0.f, aw2 = 0.f;
    float a30 = 0.f, a31 = 0.f, a32 = 0.f, aw3 = 0.f;

    // 441 = 9*28 + 7*27: workers 0..8 take 28 taps, 9..15 take 27.
    const int ntap = (w < 9) ? 28 : 27;
    int i = 0, j = w, Q = 440 - w;          // w < 16 < 21
    #pragma unroll 4
    for (int k = 0; k < ntap; ++k) {
        int py  = y + i - CC;
        int pyc = py < 0 ? 0 : (py > H - 1 ? H - 1 : py);   // addr-safe row
        int c0  = 4 * t + j - CC;            // kern/data col of elem 0
        // c0 < 0 only for j < 10, where Q >= 1 -> address stays in-bounds;
        // c0 > 124 overhangs into adjacent real kern floats (x0 = exact +0).
        f4u g = *reinterpret_cast<const f4u*>(
            kbase + ((Q << 14) + (pyc << 7) + c0));
        float e0 = __expf(g.v[0]);
        float e1 = __expf(g.v[1]);
        float e2 = __expf(g.v[2]);
        float e3 = __expf(g.v[3]);
        const unsigned char* dp = dtB + (unsigned)(i * PW + 4 * t + j) * 8;
        half4v d0 = *reinterpret_cast<const half4v*>(dp +  0);
        half4v d1 = *reinterpret_cast<const half4v*>(dp +  8);
        half4v d2 = *reinterpret_cast<const half4v*>(dp + 16);
        half4v d3 = *reinterpret_cast<const half4v*>(dp + 24);
        a00 += e0 * (float)d0.x; a01 += e0 * (float)d0.y; a02 += e0 * (float)d0.z; aw0 += e0 * (float)d0.w;
        a10 += e1 * (float)d1.x; a11 += e1 * (float)d1.y; a12 += e1 * (float)d1.z; aw1 += e1 * (float)d1.w;
        a20 += e2 * (float)d2.x; a21 += e2 * (float)d2.y; a22 += e2 * (float)d2.z; aw2 += e2 * (float)d2.w;
        a30 += e3 * (float)d3.x; a31 += e3 * (float)d3.y; a32 += e3 * (float)d3.z; aw3 += e3 * (float)d3.w;
        // advance T += 16: j += 16 (mod 21, wraps at most once), Q -= 16
        j += 16; Q -= 16;
        if (j >= KS) { j -= KS; ++i; }
    }

    // ---- fixed-order cross-worker reduce (sacc aliases the data tile) ----
    __syncthreads();                          // all dt reads done
    float4* sacc = (float4*)smem;             // [16][129] float4, padded stride
    sacc[w * 129 + 4 * t + 0] = make_float4(a00, a01, a02, aw0);
    sacc[w * 129 + 4 * t + 1] = make_float4(a10, a11, a12, aw1);
    sacc[w * 129 + 4 * t + 2] = make_float4(a20, a21, a22, aw2);
    sacc[w * 129 + 4 * t + 3] = make_float4(a30, a31, a32, aw3);
    __syncthreads();
    if (tid < W) {
        const int px = tid;
        float r0 = 0.f, r1 = 0.f, r2 = 0.f, rw = 0.f;
        #pragma unroll
        for (int s = 0; s < 16; ++s) {        // fixed order -> deterministic
            float4 p = sacc[s * 129 + px];
            r0 += p.x; r1 += p.y; r2 += p.z; rw += p.w;
        }
        // OOB taps contribute exp(0)=1 each to the softmax denominator
        int nry = max(0, CC - y)  + max(0, y  - (H - 1 - CC));
        int nrx = max(0, CC - px) + max(0, px - (W - 1 - CC));
        float co = 21.f * nry + (float)((21 - nry) * nrx);
        float inv = 1.0f / (rw + co);
        const size_t o = (size_t)b * NCH * HW + (size_t)y * W + px;
        out[o]          = r0 * inv;
        out[o + HW]     = r1 * inv;
        out[o + 2 * HW] = r2 * inv;
        sumw[(size_t)b * HW + (size_t)y * W + px] = rw * inv;
    }
}

extern "C" void kernel_launch(void* const* d_in, const int* in_sizes, int n_in,
                              void* d_out, int out_size, void* d_ws, size_t ws_size,
                              hipStream_t stream)
{
    const float* data = (const float*)d_in[0];   // (4,3,128,128) f32
    const float* kern = (const float*)d_in[1];   // (4,441,128,128) f32
    float* out  = (float*)d_out;                 // (4,3,128,128)
    float* sumw = out + (size_t)B * NCH * HW;    // (4,1,128,128)

    dim3 g(H, B);
    kaw_gather<<<g, 512, 0, stream>>>(data, kern, out, sumw);
}